// Round 1
// baseline (351.943 us; speedup 1.0000x reference)
//
#include <hip/hip_runtime.h>

#define B_      8
#define N_      8192
#define M_      2048
#define S_      32
#define C_FEAT  128
#define C_OUT   131   // 3 + 128
#define G_      8     // queries (consecutive m) per group-block

// Transposed features (b, n, c), f32 — module-owned static device memory (33.5 MB).
__device__ float g_ft[(size_t)B_ * N_ * C_FEAT];
// Per-slot selection: {px, py, pz, __int_as_float(n)} — 8.4 MB.
__device__ float4 g_selc[(size_t)B_ * M_ * S_];

typedef float f32x4_t __attribute__((ext_vector_type(4)));
__device__ __forceinline__ void store_nt(float* p, float4 v) {
    f32x4_t x; x.x = v.x; x.y = v.y; x.z = v.z; x.w = v.w;
    __builtin_nontemporal_store(x, (f32x4_t*)p);
}

// features (B, C, N) -> g_ft (B, N, C). 64x64 f32 tile, float4 global access both
// sides (256 B segments/row vs the old 128 B). tile pitch 68: float4 stores land
// 8 lanes / 4-bank group = LDS-optimal; scalar reads ~8-way but LDS is not the
// bottleneck here (~0.5 us/CU vs ~11 us global).
__global__ __launch_bounds__(256) void transpose_kernel(
    const float* __restrict__ f)
{
    __shared__ float tile[64][68];
    int t = threadIdx.x;
    int n0 = blockIdx.x * 64, c0 = blockIdx.y * 64, b = blockIdx.z;

    int nt = t & 15, cr0 = t >> 4;            // 16 float4 cols (64 n), 16 c-rows/pass
    #pragma unroll
    for (int pass = 0; pass < 4; ++pass) {
        int cr = cr0 + pass * 16;
        float4 v = *((const float4*)&f[((size_t)(b * C_FEAT + c0 + cr)) * N_ + n0 + nt * 4]);
        *((float4*)&tile[cr][nt * 4]) = v;    // byte pitch 272 = 17*16, 16B-aligned
    }
    __syncthreads();
    int ct = t & 15, nr0 = t >> 4;            // 16 float4 cols (64 c), 16 n-rows/pass
    #pragma unroll
    for (int pass = 0; pass < 4; ++pass) {
        int nr = nr0 + pass * 16;
        float4 v;
        v.x = tile[ct*4+0][nr];
        v.y = tile[ct*4+1][nr];
        v.z = tile[ct*4+2][nr];
        v.w = tile[ct*4+3][nr];
        *((float4*)&g_ft[((size_t)(b * N_ + n0 + nr)) * C_FEAT + c0 + ct * 4]) = v;
    }
}

// One 256-thread block per query (b,m). Scan only; writes 32 float4 selection slots.
// !!! DISTANCE BLOCK IS BIT-EXACT vs THE numpy-f32 REFERENCE — DO NOT TOUCH !!!
//   qq, pp: forward sequential  ((x^2 + y^2) + z^2)      [np pairwise_sum n<8]
//   dot:    REVERSED sequential ((z*z' + y*y') + x*x')   [np einsum d=3
//           descending switch-fallthrough remainder, scalar mul+add, no FMA]
//   dist = fl32( fl32(qq+pp) - fl32(2*dot) );  mask = dist < f32(0.04) strict
// Round 6 (prev session): passed with absmax = 0.0 under exactly this formulation.
__global__ __launch_bounds__(256) void ballq_kernel(
    const float* __restrict__ xyz,
    const float* __restrict__ new_xyz)
{
    __shared__ unsigned long long s_mask[8];
    __shared__ int s_fin[32];
    __shared__ float s_cx[32], s_cy[32], s_cz[32];   // coords of selected points

    // XCD-aware swizzle: b = blockIdx&7 pins each batch to one XCD (L2 locality
    // for the xyz scan). Bijective remap, speed heuristic only.
    unsigned i = blockIdx.x;
    unsigned b = i & 7u, m = i >> 3;      // qid = b*2048 + m
    unsigned w = threadIdx.x >> 6, lane = threadIdx.x & 63u;

    const float* q = new_xyz + (b * M_ + m) * 3;
    float qx = q[0], qy = q[1], qz = q[2];
    float qq = __fadd_rn(__fadd_rn(__fmul_rn(qx,qx), __fmul_rn(qy,qy)), __fmul_rn(qz,qz));

    const float* P = xyz + (size_t)b * N_ * 3;

    int done = 0;   // uniform across the block
    for (int base = 0; base < N_ && done < S_; base += 512) {
        // eval 0 covers [base, base+256), eval 1 covers [base+256, base+512);
        // global ascending order = (eval, wave, lane-bit).
        int n0 = base + (int)(w * 64u + lane);
        int n1 = n0 + 256;
        float px0 = P[n0*3+0], py0 = P[n0*3+1], pz0 = P[n0*3+2];
        float px1 = P[n1*3+0], py1 = P[n1*3+1], pz1 = P[n1*3+2];

        float pp0 = __fadd_rn(__fadd_rn(__fmul_rn(px0,px0), __fmul_rn(py0,py0)), __fmul_rn(pz0,pz0));
        float dt0 = __fadd_rn(__fadd_rn(__fmul_rn(qz,pz0), __fmul_rn(qy,py0)), __fmul_rn(qx,px0));
        float d0  = __fsub_rn(__fadd_rn(qq, pp0), __fmul_rn(2.0f, dt0));
        float pp1 = __fadd_rn(__fadd_rn(__fmul_rn(px1,px1), __fmul_rn(py1,py1)), __fmul_rn(pz1,pz1));
        float dt1 = __fadd_rn(__fadd_rn(__fmul_rn(qz,pz1), __fmul_rn(qy,py1)), __fmul_rn(qx,px1));
        float d1  = __fsub_rn(__fadd_rn(qq, pp1), __fmul_rn(2.0f, dt1));

        unsigned long long mk0 = __ballot(d0 < 0.04f);   // strict <, f32(0.04)
        unsigned long long mk1 = __ballot(d1 < 0.04f);
        if (lane == 0) { s_mask[w] = mk0; s_mask[4 + w] = mk1; }
        __syncthreads();

        int c[8], tot = 0;
        #pragma unroll
        for (int k = 0; k < 8; k++) { c[k] = __popcll(s_mask[k]); tot += c[k]; }
        int pre0 = done, pre1 = done;
        #pragma unroll
        for (int k = 0; k < 8; k++) {
            if (k < (int)w)     pre0 += c[k];
            if (k < (int)(4+w)) pre1 += c[k];
        }
        if ((mk0 >> lane) & 1ull) {
            int slot = pre0 + __popcll(mk0 & ((1ull << lane) - 1ull));
            if (slot < S_) { s_fin[slot] = n0; s_cx[slot] = px0; s_cy[slot] = py0; s_cz[slot] = pz0; }
        }
        if ((mk1 >> lane) & 1ull) {
            int slot = pre1 + __popcll(mk1 & ((1ull << lane) - 1ull));
            if (slot < S_) { s_fin[slot] = n1; s_cx[slot] = px1; s_cy[slot] = py1; s_cz[slot] = pz1; }
        }
        done += tot;                              // uniform
        __syncthreads();                          // s_fin/s_c* done; s_mask reusable
    }

    // Pad: slots [total,32) <- slot 0's index+coords if any valid, else idx 0.
    int total = (done < S_) ? done : S_;
    if ((int)threadIdx.x >= total && threadIdx.x < S_) {
        if (done > 0) {
            s_fin[threadIdx.x] = s_fin[0];
            s_cx[threadIdx.x] = s_cx[0]; s_cy[threadIdx.x] = s_cy[0]; s_cz[threadIdx.x] = s_cz[0];
        } else {
            s_fin[threadIdx.x] = 0;
            s_cx[threadIdx.x] = P[0]; s_cy[threadIdx.x] = P[1]; s_cz[threadIdx.x] = P[2];
        }
    }
    __syncthreads();

    if (threadIdx.x < S_) {
        int s = (int)threadIdx.x;
        float4 v;
        v.x = s_cx[s]; v.y = s_cy[s]; v.z = s_cz[s];
        v.w = __int_as_float(s_fin[s]);
        g_selc[((size_t)(b * M_ + m)) * S_ + s] = v;   // 512 B contiguous per block
    }
}

// Group + write: one 512-thread block per 8 consecutive m (same b) => every
// channel's store run is 8 m x 32 s x 4 B = 1024 B contiguous (vs 128 B before).
// Features staged through LDS in 4 chunks of 32 channels (32 KB).
__global__ __launch_bounds__(512, 4) void group_kernel(
    const float* __restrict__ new_xyz,
    float* __restrict__ out)
{
    __shared__ float s_cx[G_][33], s_cy[G_][33], s_cz[G_][33];
    __shared__ int   s_fin[G_][33];
    __shared__ float sT[32][256];   // [chunk-local channel][q*32+s]

    unsigned i = blockIdx.x;
    unsigned b = i & 7u;              // same XCD pinning as ballq
    unsigned m0 = (i >> 3) * G_;
    unsigned t = threadIdx.x;

    if (t < 256) {
        float4 v = g_selc[((size_t)(b * M_ + m0)) * S_ + t];   // 4 KB contiguous
        unsigned qi = t >> 5, s = t & 31u;
        s_cx[qi][s] = v.x; s_cy[qi][s] = v.y; s_cz[qi][s] = v.z;
        s_fin[qi][s] = __float_as_int(v.w);
    }
    __syncthreads();

    // Coord channels 0..2: 3 waves, each writes 8 m x 32 s = 1024 B contiguous.
    if (t < 192) {
        unsigned ch = t >> 6, l = t & 63u, qi = l >> 3, s4 = (l & 7u) * 4u;
        float qc = new_xyz[((size_t)(b * M_ + m0 + qi)) * 3 + ch];
        const float* sc = (ch == 0) ? s_cx[qi] : (ch == 1) ? s_cy[qi] : s_cz[qi];
        float4 v;
        v.x = __fsub_rn(sc[s4 + 0], qc);
        v.y = __fsub_rn(sc[s4 + 1], qc);
        v.z = __fsub_rn(sc[s4 + 2], qc);
        v.w = __fsub_rn(sc[s4 + 3], qc);
        size_t off = (((size_t)(b * C_OUT + ch)) * M_ + (m0 + qi)) * S_ + s4;
        store_nt(out + off, v);
    }

    // Feature channels: pair p=(q,s) per 2 threads; each thread reads 64 B
    // (16 consecutive channels) of the 512 B row per chunk.
    unsigned p = t >> 1, h = t & 1u;
    unsigned qg = p >> 5, sg = p & 31u;
    const float* grow = g_ft + ((size_t)(b * N_ + s_fin[qg][sg])) * C_FEAT + h * 16u;

    for (int k = 0; k < 4; ++k) {
        const float4* src = (const float4*)(grow + k * 32);
        float4 v0 = src[0], v1 = src[1], v2 = src[2], v3 = src[3];
        unsigned cb = h * 16u;
        // Scatter into sT: lanes 2p,2p+1 share a bank (2-way aliasing = free).
        sT[cb +  0][p] = v0.x; sT[cb +  1][p] = v0.y; sT[cb +  2][p] = v0.z; sT[cb +  3][p] = v0.w;
        sT[cb +  4][p] = v1.x; sT[cb +  5][p] = v1.y; sT[cb +  6][p] = v1.z; sT[cb +  7][p] = v1.w;
        sT[cb +  8][p] = v2.x; sT[cb +  9][p] = v2.y; sT[cb + 10][p] = v2.z; sT[cb + 11][p] = v2.w;
        sT[cb + 12][p] = v3.x; sT[cb + 13][p] = v3.y; sT[cb + 14][p] = v3.z; sT[cb + 15][p] = v3.w;
        __syncthreads();
        #pragma unroll
        for (int rep = 0; rep < 4; ++rep) {
            unsigned idx = rep * 512u + t;          // 0..2047 = 32 ch x 64 float4
            unsigned chl = idx >> 6;                // wave-uniform channel
            unsigned l4  = (idx & 63u) * 4u;        // float offset within 1 KB run
            float4 v = *((const float4*)&sT[chl][l4]);   // contiguous b128, no conflict
            size_t off = (((size_t)(b * C_OUT + 3 + k * 32 + chl)) * M_ + m0) * S_ + l4;
            store_nt(out + off, v);
        }
        __syncthreads();   // protect sT before next chunk's scatter
    }
}

extern "C" void kernel_launch(void* const* d_in, const int* in_sizes, int n_in,
                              void* d_out, int out_size, void* d_ws, size_t ws_size,
                              hipStream_t stream) {
    const float* xyz      = (const float*)d_in[0];  // (8,8192,3) f32
    const float* new_xyz  = (const float*)d_in[1];  // (8,2048,3) f32
    const float* features = (const float*)d_in[2];  // (8,128,8192) f32
    float* out = (float*)d_out;                     // (8,131,2048,32) f32

    transpose_kernel<<<dim3(N_ / 64, C_FEAT / 64, B_), dim3(256), 0, stream>>>(features);
    ballq_kernel<<<dim3(B_ * M_), dim3(256), 0, stream>>>(xyz, new_xyz);
    group_kernel<<<dim3(B_ * M_ / G_), dim3(512), 0, stream>>>(new_xyz, out);
}

// Round 2
// 324.196 us; speedup vs baseline: 1.0856x; 1.0856x over previous
//
#include <hip/hip_runtime.h>

#define B_      8
#define N_      8192
#define M_      2048
#define S_      32
#define C_FEAT  128
#define C_OUT   131   // 3 + 128
#define G_      8     // queries (consecutive m) per block

// Transposed features (b, n, c), f32 — module-owned static device memory (33.5 MB).
__device__ float g_ft[(size_t)B_ * N_ * C_FEAT];

typedef float f32x4_t __attribute__((ext_vector_type(4)));
__device__ __forceinline__ void store_nt(float* p, float4 v) {
    f32x4_t x; x.x = v.x; x.y = v.y; x.z = v.z; x.w = v.w;
    __builtin_nontemporal_store(x, (f32x4_t*)p);
}

// features (B, C, N) -> g_ft (B, N, C). 64x64 f32 tile, float4 global access both
// sides (256 B segments/row). Verified round 1.
__global__ __launch_bounds__(256) void transpose_kernel(
    const float* __restrict__ f)
{
    __shared__ float tile[64][68];
    int t = threadIdx.x;
    int n0 = blockIdx.x * 64, c0 = blockIdx.y * 64, b = blockIdx.z;

    int nt = t & 15, cr0 = t >> 4;            // 16 float4 cols (64 n), 16 c-rows/pass
    #pragma unroll
    for (int pass = 0; pass < 4; ++pass) {
        int cr = cr0 + pass * 16;
        float4 v = *((const float4*)&f[((size_t)(b * C_FEAT + c0 + cr)) * N_ + n0 + nt * 4]);
        *((float4*)&tile[cr][nt * 4]) = v;    // byte pitch 272 = 17*16, 16B-aligned
    }
    __syncthreads();
    int ct = t & 15, nr0 = t >> 4;            // 16 float4 cols (64 c), 16 n-rows/pass
    #pragma unroll
    for (int pass = 0; pass < 4; ++pass) {
        int nr = nr0 + pass * 16;
        float4 v;
        v.x = tile[ct*4+0][nr];
        v.y = tile[ct*4+1][nr];
        v.z = tile[ct*4+2][nr];
        v.w = tile[ct*4+3][nr];
        *((float4*)&g_ft[((size_t)(b * N_ + n0 + nr)) * C_FEAT + c0 + ct * 4]) = v;
    }
}

// One 512-thread block per 8 consecutive m (same b).
// Phase 1: wave w scans query m0+w (64-point ballot rounds, no block barriers).
// Phase 2: round-1's verified group/write structure (1 KB contiguous NT stores),
// with chunk k+1's gather loads pipelined over chunk k's store phase.
//
// !!! DISTANCE BLOCK IS BIT-EXACT vs THE numpy-f32 REFERENCE — DO NOT TOUCH !!!
//   qq, pp: forward sequential  ((x^2 + y^2) + z^2)      [np pairwise_sum n<8]
//   dot:    REVERSED sequential ((z*z' + y*y') + x*x')   [np einsum d=3
//           descending switch-fallthrough remainder, scalar mul+add, no FMA]
//   dist = fl32( fl32(qq+pp) - fl32(2*dot) );  mask = dist < f32(0.04) strict
// Selection order: ascending rounds x ascending lane = ascending n, identical
// prefix-popcount slotting + batch-granularity early exit as the verified r0/r1.
__global__ __launch_bounds__(512, 4) void fused_kernel(
    const float* __restrict__ xyz,
    const float* __restrict__ new_xyz,
    float* __restrict__ out)
{
    __shared__ float4 s_sel[G_][S_];   // {px,py,pz,__int_as_float(n)} per slot
    __shared__ float  s_q[G_][3];
    __shared__ int    s_done[G_];
    __shared__ float  sT[32][256];     // [chunk-local channel][q*32+s]

    // XCD pinning: b = blockIdx&7 puts all of batch b's blocks on one XCD; the
    // hot g_ft rows (low n, ~1-2 MB/batch) stay resident in that XCD's 4 MB L2.
    unsigned i = blockIdx.x;
    unsigned b = i & 7u;
    unsigned m0 = (i >> 3) * G_;
    unsigned t = threadIdx.x;
    unsigned w = t >> 6, lane = t & 63u;

    // ---- Phase 1: per-wave ball-query scan ----
    const float* q = new_xyz + ((size_t)(b * M_ + m0 + w)) * 3;
    float qx = q[0], qy = q[1], qz = q[2];
    if (lane == 0) { s_q[w][0] = qx; s_q[w][1] = qy; s_q[w][2] = qz; }
    float qq = __fadd_rn(__fadd_rn(__fmul_rn(qx,qx), __fmul_rn(qy,qy)), __fmul_rn(qz,qz));
    const float* P = xyz + (size_t)b * N_ * 3;

    int done = 0;   // wave-uniform
    for (int nb = 0; nb < N_ && done < S_; nb += 256) {
        float px[4], py[4], pz[4];
        #pragma unroll
        for (int r = 0; r < 4; ++r) {      // all 12 loads issued up front
            int n = nb + r * 64 + (int)lane;
            px[r] = P[n*3+0]; py[r] = P[n*3+1]; pz[r] = P[n*3+2];
        }
        #pragma unroll
        for (int r = 0; r < 4; ++r) {
            float pp = __fadd_rn(__fadd_rn(__fmul_rn(px[r],px[r]), __fmul_rn(py[r],py[r])), __fmul_rn(pz[r],pz[r]));
            float dt = __fadd_rn(__fadd_rn(__fmul_rn(qz,pz[r]), __fmul_rn(qy,py[r])), __fmul_rn(qx,px[r]));
            float d  = __fsub_rn(__fadd_rn(qq, pp), __fmul_rn(2.0f, dt));
            unsigned long long mk = __ballot(d < 0.04f);   // strict <, f32(0.04)
            if ((mk >> lane) & 1ull) {
                int slot = done + __popcll(mk & ((1ull << lane) - 1ull));
                if (slot < S_) {
                    float4 v;
                    v.x = px[r]; v.y = py[r]; v.z = pz[r];
                    v.w = __int_as_float(nb + r * 64 + (int)lane);
                    s_sel[w][slot] = v;
                }
            }
            done += (int)__popcll(mk);
        }
    }
    if (lane == 0) s_done[w] = done;
    __syncthreads();

    // ---- Pad: slots [total,32) <- slot 0 if any valid, else {P[0..2], 0} ----
    if (t < 256) {
        int w2 = (int)(t >> 5), s = (int)(t & 31u);
        int dn = s_done[w2];
        int total = dn < S_ ? dn : S_;
        if (s >= total) {
            float4 v;
            if (dn > 0) v = s_sel[w2][0];   // slot 0 not written here when dn>0
            else { v.x = P[0]; v.y = P[1]; v.z = P[2]; v.w = __int_as_float(0); }
            s_sel[w2][s] = v;
        }
    }
    __syncthreads();

    // ---- Phase 2a: coord channels 0..2 (3 waves x 8 m x 32 s = 1 KB runs) ----
    if (t < 192) {
        unsigned ch = t >> 6, l = t & 63u, qi = l >> 3, s4 = (l & 7u) * 4u;
        float qc = s_q[qi][ch];
        const float* sp = (const float*)&s_sel[qi][0];
        float4 v;
        v.x = __fsub_rn(sp[(s4 + 0) * 4 + ch], qc);
        v.y = __fsub_rn(sp[(s4 + 1) * 4 + ch], qc);
        v.z = __fsub_rn(sp[(s4 + 2) * 4 + ch], qc);
        v.w = __fsub_rn(sp[(s4 + 3) * 4 + ch], qc);
        size_t off = (((size_t)(b * C_OUT + ch)) * M_ + (m0 + qi)) * S_ + s4;
        store_nt(out + off, v);
    }

    // ---- Phase 2b: feature channels, 4 chunks of 32, pipelined gather ----
    unsigned p = t >> 1, h = t & 1u;           // pair per (q,s); 64 B halves
    unsigned qg = p >> 5, sg = p & 31u;
    float4 selv = s_sel[qg][sg];               // b128 read, conflict-free
    int n = __float_as_int(selv.w);
    const float* grow = g_ft + ((size_t)(b * N_ + n)) * C_FEAT + h * 16u;

    float4 r0 = ((const float4*)grow)[0];
    float4 r1 = ((const float4*)grow)[1];
    float4 r2 = ((const float4*)grow)[2];
    float4 r3 = ((const float4*)grow)[3];

    for (int k = 0; k < 4; ++k) {
        float4 n0, n1, n2, n3;
        if (k < 3) {                           // prefetch chunk k+1 (T14)
            const float4* src = (const float4*)(grow + (k + 1) * 32);
            n0 = src[0]; n1 = src[1]; n2 = src[2]; n3 = src[3];
        }
        unsigned cb = h * 16u;
        // Scatter: lanes 2p,2p+1 share a bank (2-way aliasing = free).
        sT[cb +  0][p] = r0.x; sT[cb +  1][p] = r0.y; sT[cb +  2][p] = r0.z; sT[cb +  3][p] = r0.w;
        sT[cb +  4][p] = r1.x; sT[cb +  5][p] = r1.y; sT[cb +  6][p] = r1.z; sT[cb +  7][p] = r1.w;
        sT[cb +  8][p] = r2.x; sT[cb +  9][p] = r2.y; sT[cb + 10][p] = r2.z; sT[cb + 11][p] = r2.w;
        sT[cb + 12][p] = r3.x; sT[cb + 13][p] = r3.y; sT[cb + 14][p] = r3.z; sT[cb + 15][p] = r3.w;
        __syncthreads();
        #pragma unroll
        for (int rep = 0; rep < 4; ++rep) {
            unsigned idx = rep * 512u + t;     // 32 ch x 64 float4
            unsigned chl = idx >> 6;           // wave-uniform channel
            unsigned l4  = (idx & 63u) * 4u;   // float offset in the 1 KB run
            float4 v = *((const float4*)&sT[chl][l4]);   // contiguous b128
            size_t off = (((size_t)(b * C_OUT + 3 + k * 32 + chl)) * M_ + m0) * S_ + l4;
            store_nt(out + off, v);
        }
        __syncthreads();   // protect sT before next chunk's scatter
        r0 = n0; r1 = n1; r2 = n2; r3 = n3;
    }
}

extern "C" void kernel_launch(void* const* d_in, const int* in_sizes, int n_in,
                              void* d_out, int out_size, void* d_ws, size_t ws_size,
                              hipStream_t stream) {
    const float* xyz      = (const float*)d_in[0];  // (8,8192,3) f32
    const float* new_xyz  = (const float*)d_in[1];  // (8,2048,3) f32
    const float* features = (const float*)d_in[2];  // (8,128,8192) f32
    float* out = (float*)d_out;                     // (8,131,2048,32) f32

    transpose_kernel<<<dim3(N_ / 64, C_FEAT / 64, B_), dim3(256), 0, stream>>>(features);
    fused_kernel<<<dim3(B_ * M_ / G_), dim3(512), 0, stream>>>(xyz, new_xyz, out);
}

// Round 4
// 323.311 us; speedup vs baseline: 1.0886x; 1.0027x over previous
//
#include <hip/hip_runtime.h>

#define B_      8
#define N_      8192
#define M_      2048
#define S_      32
#define C_FEAT  128
#define C_OUT   131   // 3 + 128
#define G_      8     // queries (consecutive m) per block

// Transposed features (b, n, c), f32 — module-owned static device memory (33.5 MB).
__device__ float g_ft[(size_t)B_ * N_ * C_FEAT];

typedef float f32x4_t __attribute__((ext_vector_type(4)));
__device__ __forceinline__ void store_nt(float* p, float4 v) {
    f32x4_t x; x.x = v.x; x.y = v.y; x.z = v.z; x.w = v.w;
    __builtin_nontemporal_store(x, (f32x4_t*)p);
}

// Barrier that does NOT drain vmcnt: LDS deps are ordered by lgkmcnt(0); in-flight
// global loads (prefetch) and NT stores stay in flight across it. Safe here because
// each wave's ds_reads are consumed (by stores) before it reaches the barrier, and
// ds ops from one wave execute in order in the LDS pipe.
__device__ __forceinline__ void lds_barrier() {
    asm volatile("s_waitcnt lgkmcnt(0)" ::: "memory");
    __builtin_amdgcn_s_barrier();
}

// features (B, C, N) -> g_ft (B, N, C). 64x64 f32 tile, float4 both sides.
// Grid linearized so b = blockIdx&7 (same XCD pinning as fused_kernel) and n-tiles
// run in REVERSE: the hot low-n rows (ball-query selections concentrate there) are
// the most-recently-written lines in XCD b's L2 when the gather starts.
__global__ __launch_bounds__(256) void transpose_kernel(
    const float* __restrict__ f)
{
    __shared__ float tile[64][68];
    unsigned x = blockIdx.x;
    int b = (int)(x & 7u);
    unsigned r = x >> 3;                      // 0..255 = (n-tile, c-tile)
    int c0 = (int)(r & 1u) * 64;
    int n0 = (127 - (int)(r >> 1)) * 64;      // reverse: low n written last
    int t = threadIdx.x;

    int nt = t & 15, cr0 = t >> 4;            // 16 float4 cols (64 n), 16 c-rows/pass
    #pragma unroll
    for (int pass = 0; pass < 4; ++pass) {
        int cr = cr0 + pass * 16;
        float4 v = *((const float4*)&f[((size_t)(b * C_FEAT + c0 + cr)) * N_ + n0 + nt * 4]);
        *((float4*)&tile[cr][nt * 4]) = v;    // byte pitch 272 = 17*16, 16B-aligned
    }
    __syncthreads();
    int ct = t & 15, nr0 = t >> 4;            // 16 float4 cols (64 c), 16 n-rows/pass
    #pragma unroll
    for (int pass = 0; pass < 4; ++pass) {
        int nr = nr0 + pass * 16;
        float4 v;
        v.x = tile[ct*4+0][nr];
        v.y = tile[ct*4+1][nr];
        v.z = tile[ct*4+2][nr];
        v.w = tile[ct*4+3][nr];
        *((float4*)&g_ft[((size_t)(b * N_ + n0 + nr)) * C_FEAT + c0 + ct * 4]) = v;
    }
}

// One 512-thread block per 8 consecutive m (same b).
// Phase 1: wave w scans query m0+w (64-point ballot rounds, no block barriers).
// Phase 2: verified group/write structure (1 KB contiguous NT stores); chunk k+1's
// gather loads are issued before chunk k's store phase and — with lds_barrier() —
// actually stay in flight across it (the old __syncthreads drained vmcnt(0)).
//
// !!! DISTANCE BLOCK IS BIT-EXACT vs THE numpy-f32 REFERENCE — DO NOT TOUCH !!!
//   qq, pp: forward sequential  ((x^2 + y^2) + z^2)      [np pairwise_sum n<8]
//   dot:    REVERSED sequential ((z*z' + y*y') + x*x')   [np einsum d=3
//           descending switch-fallthrough remainder, scalar mul+add, no FMA]
//   dist = fl32( fl32(qq+pp) - fl32(2*dot) );  mask = dist < f32(0.04) strict
// Selection order: ascending rounds x ascending lane = ascending n, identical
// prefix-popcount slotting + batch-granularity early exit as the verified r0-r2.
__global__ __launch_bounds__(512, 4) void fused_kernel(
    const float* __restrict__ xyz,
    const float* __restrict__ new_xyz,
    float* __restrict__ out)
{
    __shared__ float4 s_sel[G_][S_];   // {px,py,pz,__int_as_float(n)} per slot
    __shared__ float  s_q[G_][3];
    __shared__ int    s_done[G_];
    __shared__ float  sT[32][256];     // [chunk-local channel][q*32+s]

    // XCD pinning: b = blockIdx&7 — matches the transpose's pinning, so the hot
    // low-n g_ft rows for batch b are XCD-local L2 hits.
    unsigned i = blockIdx.x;
    unsigned b = i & 7u;
    unsigned m0 = (i >> 3) * G_;
    unsigned t = threadIdx.x;
    unsigned w = t >> 6, lane = t & 63u;

    // ---- Phase 1: per-wave ball-query scan ----
    const float* q = new_xyz + ((size_t)(b * M_ + m0 + w)) * 3;
    float qx = q[0], qy = q[1], qz = q[2];
    if (lane == 0) { s_q[w][0] = qx; s_q[w][1] = qy; s_q[w][2] = qz; }
    float qq = __fadd_rn(__fadd_rn(__fmul_rn(qx,qx), __fmul_rn(qy,qy)), __fmul_rn(qz,qz));
    const float* P = xyz + (size_t)b * N_ * 3;

    int done = 0;   // wave-uniform
    for (int nb = 0; nb < N_ && done < S_; nb += 256) {
        float px[4], py[4], pz[4];
        #pragma unroll
        for (int r = 0; r < 4; ++r) {      // all 12 loads issued up front
            int n = nb + r * 64 + (int)lane;
            px[r] = P[n*3+0]; py[r] = P[n*3+1]; pz[r] = P[n*3+2];
        }
        #pragma unroll
        for (int r = 0; r < 4; ++r) {
            float pp = __fadd_rn(__fadd_rn(__fmul_rn(px[r],px[r]), __fmul_rn(py[r],py[r])), __fmul_rn(pz[r],pz[r]));
            float dt = __fadd_rn(__fadd_rn(__fmul_rn(qz,pz[r]), __fmul_rn(qy,py[r])), __fmul_rn(qx,px[r]));
            float d  = __fsub_rn(__fadd_rn(qq, pp), __fmul_rn(2.0f, dt));
            unsigned long long mk = __ballot(d < 0.04f);   // strict <, f32(0.04)
            if ((mk >> lane) & 1ull) {
                int slot = done + __popcll(mk & ((1ull << lane) - 1ull));
                if (slot < S_) {
                    float4 v;
                    v.x = px[r]; v.y = py[r]; v.z = pz[r];
                    v.w = __int_as_float(nb + r * 64 + (int)lane);
                    s_sel[w][slot] = v;
                }
            }
            done += (int)__popcll(mk);
        }
    }
    if (lane == 0) s_done[w] = done;
    __syncthreads();

    // ---- Pad: slots [total,32) <- slot 0 if any valid, else {P[0..2], 0} ----
    if (t < 256) {
        int w2 = (int)(t >> 5), s = (int)(t & 31u);
        int dn = s_done[w2];
        int total = dn < S_ ? dn : S_;
        if (s >= total) {
            float4 v;
            if (dn > 0) v = s_sel[w2][0];   // slot 0 not written here when dn>0
            else { v.x = P[0]; v.y = P[1]; v.z = P[2]; v.w = __int_as_float(0); }
            s_sel[w2][s] = v;
        }
    }
    __syncthreads();

    // ---- Phase 2a: coord channels 0..2 (3 waves x 8 m x 32 s = 1 KB runs) ----
    if (t < 192) {
        unsigned ch = t >> 6, l = t & 63u, qi = l >> 3, s4 = (l & 7u) * 4u;
        float qc = s_q[qi][ch];
        const float* sp = (const float*)&s_sel[qi][0];
        float4 v;
        v.x = __fsub_rn(sp[(s4 + 0) * 4 + ch], qc);
        v.y = __fsub_rn(sp[(s4 + 1) * 4 + ch], qc);
        v.z = __fsub_rn(sp[(s4 + 2) * 4 + ch], qc);
        v.w = __fsub_rn(sp[(s4 + 3) * 4 + ch], qc);
        size_t off = (((size_t)(b * C_OUT + ch)) * M_ + (m0 + qi)) * S_ + s4;
        store_nt(out + off, v);
    }

    // ---- Phase 2b: feature channels, 4 chunks of 32, pipelined gather ----
    unsigned p = t >> 1, h = t & 1u;           // pair per (q,s); 64 B halves
    unsigned qg = p >> 5, sg = p & 31u;
    float4 selv = s_sel[qg][sg];               // b128 read, conflict-free
    int n = __float_as_int(selv.w);
    const float* grow = g_ft + ((size_t)(b * N_ + n)) * C_FEAT + h * 16u;

    float4 r0 = ((const float4*)grow)[0];
    float4 r1 = ((const float4*)grow)[1];
    float4 r2 = ((const float4*)grow)[2];
    float4 r3 = ((const float4*)grow)[3];

    for (int k = 0; k < 4; ++k) {
        float4 n0, n1, n2, n3;
        if (k < 3) {                           // prefetch chunk k+1 (T14)
            const float4* src = (const float4*)(grow + (k + 1) * 32);
            n0 = src[0]; n1 = src[1]; n2 = src[2]; n3 = src[3];
        }
        unsigned cb = h * 16u;
        // Scatter: lanes 2p,2p+1 share a bank (2-way aliasing = free).
        sT[cb +  0][p] = r0.x; sT[cb +  1][p] = r0.y; sT[cb +  2][p] = r0.z; sT[cb +  3][p] = r0.w;
        sT[cb +  4][p] = r1.x; sT[cb +  5][p] = r1.y; sT[cb +  6][p] = r1.z; sT[cb +  7][p] = r1.w;
        sT[cb +  8][p] = r2.x; sT[cb +  9][p] = r2.y; sT[cb + 10][p] = r2.z; sT[cb + 11][p] = r2.w;
        sT[cb + 12][p] = r3.x; sT[cb + 13][p] = r3.y; sT[cb + 14][p] = r3.z; sT[cb + 15][p] = r3.w;
        lds_barrier();                         // scatter visible; loads/stores stay in flight
        #pragma unroll
        for (int rep = 0; rep < 4; ++rep) {
            unsigned idx = rep * 512u + t;     // 32 ch x 64 float4
            unsigned chl = idx >> 6;           // wave-uniform channel
            unsigned l4  = (idx & 63u) * 4u;   // float offset in the 1 KB run
            float4 v = *((const float4*)&sT[chl][l4]);   // contiguous b128
            size_t off = (((size_t)(b * C_OUT + 3 + k * 32 + chl)) * M_ + m0) * S_ + l4;
            store_nt(out + off, v);
        }
        if (k < 3) lds_barrier();              // protect sT before next scatter
        r0 = n0; r1 = n1; r2 = n2; r3 = n3;
    }
}

extern "C" void kernel_launch(void* const* d_in, const int* in_sizes, int n_in,
                              void* d_out, int out_size, void* d_ws, size_t ws_size,
                              hipStream_t stream) {
    const float* xyz      = (const float*)d_in[0];  // (8,8192,3) f32
    const float* new_xyz  = (const float*)d_in[1];  // (8,2048,3) f32
    const float* features = (const float*)d_in[2];  // (8,128,8192) f32
    float* out = (float*)d_out;                     // (8,131,2048,32) f32

    transpose_kernel<<<dim3((N_ / 64) * (C_FEAT / 64) * B_), dim3(256), 0, stream>>>(features);
    fused_kernel<<<dim3(B_ * M_ / G_), dim3(512), 0, stream>>>(xyz, new_xyz, out);
}